// Round 1
// 1382.801 us; speedup vs baseline: 1.4054x; 1.4054x over previous
//
#include <hip/hip_runtime.h>
#include <hip/hip_bf16.h>
#include <cstddef>

#define E_EDGES 1000000
#define N_ATOMS_C 100000
#define NC 256
#define EPS_C 1e-5f
#define INV_SQRT2 0.7071067811865476f

// ---------- bf16 helpers (raw ushort, RNE) ----------
__device__ __forceinline__ unsigned short f2bf(float x) {
    unsigned int u = __float_as_uint(x);
    unsigned int r = (u + 0x7FFFu + ((u >> 16) & 1u)) >> 16;
    return (unsigned short)r;
}
__device__ __forceinline__ float bf2f(unsigned short s) {
    return __uint_as_float(((unsigned int)s) << 16);
}

typedef __attribute__((ext_vector_type(8))) short bf16x8;   // 8 bf16 = 4 VGPR
typedef __attribute__((ext_vector_type(4))) float f32x4;

// ---------- zero the stats region ----------
__global__ void k_zero(float* __restrict__ p, int n) {
    int i = blockIdx.x * 256 + threadIdx.x;
    if (i < n) p[i] = 0.f;
}

// ---------- per-crystal edge counts via binary search (cidx sorted) ----------
__device__ __forceinline__ int lowb(const int* __restrict__ c, int n, int key) {
    int lo = 0, hi = n;
    while (lo < hi) { int m = (lo + hi) >> 1; if (c[m] < key) lo = m + 1; else hi = m; }
    return lo;
}
__global__ void k_bounds(const int* __restrict__ cidx, float* __restrict__ cntb) {
    int cr = threadIdx.x;           // 0..255
    int a = lowb(cidx, E_EDGES, cr);
    int b = lowb(cidx, E_EDGES, cr + 1);
    cntb[cr] = (float)(b - a);
}

// ---------- prep: W_full (128x128 f32, [k][f]) -> Wt (bf16, [f][k]) ----------
__global__ void k_prepw(const float* __restrict__ Wf, unsigned short* __restrict__ Wt) {
    int idx = blockIdx.x * 256 + threadIdx.x;   // 0..16383
    int f = idx >> 7, k = idx & 127;
    Wt[f * 128 + k] = f2bf(Wf[(size_t)k * 128 + f]);
}

// ---------- K1: gated = [diff||edge] @ W_full via bf16 MFMA, + stats1 ----------
// grid: 15625 tiles. block 256 (4 waves). tile = 64 edges x 128 feats.
// wave w owns output cols [w*32, w*32+32). B lives in VGPRs (loaded once).
#define TE 64
#define SAW 136   // A-tile row stride in bf16 (272 B: +16B pad -> <=2-way bank alias)
__global__ __launch_bounds__(256, 4) void k_gemm1(
    const float* __restrict__ atom, const float* __restrict__ edg,
    const int* __restrict__ nbr, const int* __restrict__ cidx,
    const unsigned short* __restrict__ Wt,
    unsigned short* __restrict__ gated,
    float* __restrict__ sum1, float* __restrict__ sq1)
{
    __shared__ __align__(16) unsigned short As[TE * SAW];   // 17.4 KB
    __shared__ int  cl[TE];
    __shared__ int2 i01[TE];

    const int e0 = blockIdx.x * TE;
    const int t  = threadIdx.x;
    const int w  = t >> 6, l = t & 63;
    const int lr = l & 15, lg = l >> 4;     // frag row/col, k-group

    if (t < TE)            cl[t]       = cidx[e0 + t];
    else if (t < 2 * TE)   i01[t - TE] = ((const int2*)nbr)[e0 + t - TE];

    // B fragments straight from global into VGPRs (W is L2/L3-hot, 32 KB total).
    // B[k][col]: lane holds k = ks*32 + lg*8 + j, col = w*32 + cf*16 + lr.
    bf16x8 bfr[4][2];
    #pragma unroll
    for (int ks = 0; ks < 4; ks++)
        #pragma unroll
        for (int cf = 0; cf < 2; cf++) {
            int col = w * 32 + cf * 16 + lr;
            bfr[ks][cf] = *(const bf16x8*)(Wt + (size_t)col * 128 + ks * 32 + lg * 8);
        }
    __syncthreads();

    // stage A tile: k 0..63 = diff (gather), k 64..127 = edge. fp32 -> bf16.
    #pragma unroll
    for (int it = 0; it < 8; it++) {
        int idx = t + it * 256;
        int e = idx >> 5, q = idx & 31;
        float4 v;
        if (q < 16) {
            int2 ii = i01[e];
            float4 a1 = *(const float4*)(atom + (size_t)ii.y * 64 + q * 4);
            float4 a0 = *(const float4*)(atom + (size_t)ii.x * 64 + q * 4);
            v = make_float4(a1.x - a0.x, a1.y - a0.y, a1.z - a0.z, a1.w - a0.w);
        } else {
            v = *(const float4*)(edg + (size_t)(e0 + e) * 64 + (q - 16) * 4);
        }
        ushort4 p;
        p.x = f2bf(v.x); p.y = f2bf(v.y); p.z = f2bf(v.z); p.w = f2bf(v.w);
        *(ushort4*)(As + e * SAW + q * 4) = p;
    }
    __syncthreads();

    // MFMA: acc[rf][cf] covers edges rf*16+[0,16), cols w*32+cf*16+[0,16)
    f32x4 acc[4][2];
    #pragma unroll
    for (int rf = 0; rf < 4; rf++)
        #pragma unroll
        for (int cf = 0; cf < 2; cf++)
            acc[rf][cf] = (f32x4){0.f, 0.f, 0.f, 0.f};

    #pragma unroll
    for (int ks = 0; ks < 4; ks++) {
        bf16x8 a[4];
        #pragma unroll
        for (int rf = 0; rf < 4; rf++)
            a[rf] = *(const bf16x8*)(As + (rf * 16 + lr) * SAW + ks * 32 + lg * 8);
        #pragma unroll
        for (int rf = 0; rf < 4; rf++)
            #pragma unroll
            for (int cf = 0; cf < 2; cf++)
                acc[rf][cf] = __builtin_amdgcn_mfma_f32_16x16x32_bf16(
                    a[rf], bfr[ks][cf], acc[rf][cf], 0, 0, 0);
    }

    // write gated bf16. C/D layout: col = lane&15, row = (lane>>4)*4 + r.
    #pragma unroll
    for (int rf = 0; rf < 4; rf++)
        #pragma unroll
        for (int cf = 0; cf < 2; cf++) {
            int col = w * 32 + cf * 16 + lr;
            #pragma unroll
            for (int r = 0; r < 4; r++) {
                int ge = e0 + rf * 16 + lg * 4 + r;
                gated[(size_t)ge * 128 + col] = f2bf(acc[rf][cf][r]);
            }
        }

    // stats1: per-feature sums are lane-local (fixed col per lane).
    const bool pure = (cl[0] == cl[TE - 1]);    // cidx sorted
    if (pure) {
        int c = cl[0];
        #pragma unroll
        for (int cf = 0; cf < 2; cf++) {
            float s = 0.f, q = 0.f;
            #pragma unroll
            for (int rf = 0; rf < 4; rf++)
                #pragma unroll
                for (int r = 0; r < 4; r++) {
                    float v = acc[rf][cf][r];
                    s += v; q += v * v;
                }
            s += __shfl_xor(s, 16); s += __shfl_xor(s, 32);
            q += __shfl_xor(q, 16); q += __shfl_xor(q, 32);
            if (lg == 0) {
                int col = w * 32 + cf * 16 + lr;
                atomicAdd(&sum1[c * 128 + col], s);
                atomicAdd(&sq1 [c * 128 + col], q);
            }
        }
    } else {
        #pragma unroll
        for (int cf = 0; cf < 2; cf++) {
            int col = w * 32 + cf * 16 + lr;
            float s = 0.f, q = 0.f;
            int cp = cl[lg * 4];
            #pragma unroll
            for (int rf = 0; rf < 4; rf++)
                #pragma unroll
                for (int r = 0; r < 4; r++) {
                    int row = rf * 16 + lg * 4 + r;
                    int cc = cl[row];
                    if (cc != cp) {
                        atomicAdd(&sum1[cp * 128 + col], s);
                        atomicAdd(&sq1 [cp * 128 + col], q);
                        s = 0.f; q = 0.f; cp = cc;
                    }
                    float v = acc[rf][cf][r];
                    s += v; q += v * v;
                }
            atomicAdd(&sum1[cp * 128 + col], s);
            atomicAdd(&sq1 [cp * 128 + col], q);
        }
    }
}

// ---------- K2: normalize1 + tanh gate -> mid, + stats2 ----------
// wave per edge (lane = feature), 4 waves/block, 64 edges per wave
__global__ __launch_bounds__(256) void k_gate(
    const unsigned short* __restrict__ gated, const int* __restrict__ cidx,
    const float* __restrict__ sum1, const float* __restrict__ sq1,
    const float* __restrict__ cntb,
    const float* __restrict__ gamma1, const float* __restrict__ beta1,
    const float* __restrict__ Wm,
    unsigned short* __restrict__ mid,
    float* __restrict__ sum2, float* __restrict__ sq2)
{
    const int w = threadIdx.x >> 6, f = threadIdx.x & 63;
    const int base = blockIdx.x * 256 + w * 64;
    const float g1c = gamma1[f], b1c = beta1[f];
    const float g1f = gamma1[64 + f], b1f = beta1[64 + f];
    const float wm = Wm[f];

    int cprev = -1, crun = -1;
    float m_c = 0.f, r_c = 0.f, m_f = 0.f, r_f = 0.f;
    float s_acc = 0.f, q_acc = 0.f;

    for (int it = 0; it < 64; it++) {
        int e = base + it;
        if (e >= E_EDGES) break;
        int c = cidx[e];                 // wave-uniform
        if (c != cprev) {
            float rc = 1.f / fmaxf(cntb[c], 1.f);
            float m1 = sum1[c * 128 + f] * rc;
            float v1 = sq1[c * 128 + f] * rc - m1 * m1;
            m_c = m1; r_c = rsqrtf(v1 + EPS_C);
            float m2 = sum1[c * 128 + 64 + f] * rc;
            float v2 = sq1[c * 128 + 64 + f] * rc - m2 * m2;
            m_f = m2; r_f = rsqrtf(v2 + EPS_C);
            cprev = c;
        }
        float core = bf2f(gated[(size_t)e * 128 + f]);
        float filt = bf2f(gated[(size_t)e * 128 + 64 + f]);
        float cn = (core - m_c) * r_c * g1c + b1c;
        float fn = (filt - m_f) * r_f * g1f + b1f;
        float p = fn * wm;
        #pragma unroll
        for (int o = 32; o > 0; o >>= 1) p += __shfl_xor(p, o, 64);
        float th = tanhf(p);
        float v = th * fmaxf(cn, 0.f);
        mid[(size_t)e * 64 + f] = f2bf(v);
        if (c != crun) {
            if (crun >= 0) {
                atomicAdd(&sum2[crun * 64 + f], s_acc);
                atomicAdd(&sq2 [crun * 64 + f], q_acc);
            }
            s_acc = 0.f; q_acc = 0.f; crun = c;
        }
        s_acc += v; q_acc += v * v;
    }
    if (crun >= 0) {
        atomicAdd(&sum2[crun * 64 + f], s_acc);
        atomicAdd(&sq2 [crun * 64 + f], q_acc);
    }
}

// ---------- K3: normalize2 + 2 residual MLPs + final relu ----------
// thread per edge; x[64],h[32] in VGPRs; weights wave-uniform -> scalar loads
__global__ __launch_bounds__(256) void k_mlp(
    const unsigned short* __restrict__ mid, const int* __restrict__ cidx,
    const float* __restrict__ edg,
    const float* __restrict__ sum2, const float* __restrict__ sq2,
    const float* __restrict__ cntb,
    const float* __restrict__ gamma2, const float* __restrict__ beta2,
    const float* __restrict__ rW1, const float* __restrict__ rB1,
    const float* __restrict__ rW2, const float* __restrict__ rB2,
    float* __restrict__ out)
{
    int e = blockIdx.x * 256 + threadIdx.x;
    if (e >= E_EDGES) return;
    int c = cidx[e];
    float rc = 1.f / fmaxf(cntb[c], 1.f);

    float x[64];
    const unsigned short* mrow = mid + (size_t)e * 64;
    #pragma unroll
    for (int q = 0; q < 16; q++) {
        unsigned long long u = *(const unsigned long long*)(mrow + q * 4);
        #pragma unroll
        for (int j = 0; j < 4; j++) {
            int f = q * 4 + j;
            float xv = bf2f((unsigned short)(u >> (16 * j)));
            float m = sum2[c * 64 + f] * rc;
            float vv = sq2[c * 64 + f] * rc - m * m;
            x[f] = (xv - m) * rsqrtf(vv + EPS_C) * gamma2[f] + beta2[f];
        }
    }
    #pragma unroll
    for (int i = 0; i < 2; i++) {
        float h[32];
        #pragma unroll
        for (int j = 0; j < 32; j++) h[j] = rB1[i * 32 + j];
        #pragma unroll
        for (int f = 0; f < 64; f++) {
            const float* wrow = rW1 + i * 2048 + f * 32;   // uniform -> s_load
            float xv = x[f];
            #pragma unroll
            for (int j = 0; j < 32; j++) h[j] = fmaf(xv, wrow[j], h[j]);
        }
        #pragma unroll
        for (int j = 0; j < 32; j++) h[j] = fmaxf(h[j], 0.f);
        #pragma unroll
        for (int f = 0; f < 64; f++) x[f] += rB2[i * 64 + f];
        #pragma unroll
        for (int j = 0; j < 32; j++) {
            const float* wrow = rW2 + i * 2048 + j * 64;   // uniform -> s_load
            float hv = h[j];
            #pragma unroll
            for (int f = 0; f < 64; f++) x[f] = fmaf(hv, wrow[f], x[f]);
        }
    }
    const float* erow = edg + (size_t)e * 64;
    float* orow = out + (size_t)e * 64;
    #pragma unroll
    for (int q = 0; q < 16; q++) {
        float4 ev = *(const float4*)(erow + q * 4);
        float4 o;
        o.x = INV_SQRT2 * fmaxf(ev.x + x[q * 4 + 0], 0.f);
        o.y = INV_SQRT2 * fmaxf(ev.y + x[q * 4 + 1], 0.f);
        o.z = INV_SQRT2 * fmaxf(ev.z + x[q * 4 + 2], 0.f);
        o.w = INV_SQRT2 * fmaxf(ev.w + x[q * 4 + 3], 0.f);
        *(float4*)(orow + q * 4) = o;
    }
}

extern "C" void kernel_launch(void* const* d_in, const int* in_sizes, int n_in,
                              void* d_out, int out_size, void* d_ws, size_t ws_size,
                              hipStream_t stream)
{
    const float* atom   = (const float*)d_in[0];
    const float* edg    = (const float*)d_in[1];
    const int*   nbr    = (const int*)d_in[2];
    const int*   cidx   = (const int*)d_in[3];
    const float* Wf     = (const float*)d_in[4];
    const float* Wm     = (const float*)d_in[5];
    const float* gamma1 = (const float*)d_in[6];
    const float* beta1  = (const float*)d_in[7];
    const float* gamma2 = (const float*)d_in[8];
    const float* beta2  = (const float*)d_in[9];
    const float* rW1    = (const float*)d_in[10];
    const float* rB1    = (const float*)d_in[11];
    const float* rW2    = (const float*)d_in[12];
    const float* rB2    = (const float*)d_in[13];
    float* out = (float*)d_out;

    char* ws = (char*)d_ws;
    unsigned short* gated = (unsigned short*)ws;                               // E*128 bf16
    unsigned short* mid   = (unsigned short*)(ws + (size_t)E_EDGES * 128 * 2); // E*64 bf16
    float* stats = (float*)(ws + (size_t)E_EDGES * 128 * 2 + (size_t)E_EDGES * 64 * 2);
    float* sum1 = stats;                 // 256*128
    float* sq1  = sum1 + 256 * 128;      // 256*128
    float* sum2 = sq1 + 256 * 128;       // 256*64
    float* sq2  = sum2 + 256 * 64;       // 256*64
    float* cntb = sq2 + 256 * 64;        // 256
    unsigned short* Wt = (unsigned short*)(cntb + 256);   // 128*128 bf16 (16B-aligned)

    const int nstat = 2 * 256 * 128 + 2 * 256 * 64;
    k_zero<<<(nstat + 255) / 256, 256, 0, stream>>>(sum1, nstat);
    k_bounds<<<1, 256, 0, stream>>>(cidx, cntb);
    k_prepw<<<64, 256, 0, stream>>>(Wf, Wt);
    k_gemm1<<<E_EDGES / TE, 256, 0, stream>>>(atom, edg, nbr, cidx, Wt, gated, sum1, sq1);
    k_gate<<<(E_EDGES + 255) / 256, 256, 0, stream>>>(gated, cidx, sum1, sq1, cntb,
                                                      gamma1, beta1, Wm, mid, sum2, sq2);
    k_mlp<<<(E_EDGES + 255) / 256, 256, 0, stream>>>(mid, cidx, edg, sum2, sq2, cntb,
                                                     gamma2, beta2, rW1, rB1, rW2, rB2, out);
}